// Round 6
// baseline (439.164 us; speedup 1.0000x reference)
//
#include <hip/hip_runtime.h>
#include <hip/hip_bf16.h>
#include <cstdint>
#include <cstddef>

#define C_CLS   100000
#define D_FEAT  512
#define B_ROWS  512
#define NBN     782          /* ceil(100000/128) */

#define COSM 0.8775825618903728f
#define SINM 0.479425538604203f
#define TH_  (-0.8775825618903728f)
#define MM_  0.2397127693021015f   /* sin(0.5)*0.5 */

typedef __bf16 bf16x8 __attribute__((ext_vector_type(8)));
typedef __bf16 bf16x4 __attribute__((ext_vector_type(4)));
typedef float  f32x4  __attribute__((ext_vector_type(4)));
typedef float  f32x16 __attribute__((ext_vector_type(16)));

typedef __attribute__((address_space(3))) void lds_void;
typedef const __attribute__((address_space(1))) void g_void;

__device__ __forceinline__ void async_copy16(const void* g, void* l) {
    __builtin_amdgcn_global_load_lds((g_void*)g, (lds_void*)l, 16, 0, 0);
}

// ---------------- kernel 1: normalize x rows -> bf16, zero output --------
__global__ void k_xnorm(const float* __restrict__ x, __bf16* __restrict__ xn,
                        float* __restrict__ out) {
    const int row  = blockIdx.x;          // 512 blocks
    const int lane = threadIdx.x;         // 64 threads
    if (row == 0 && lane == 0) out[0] = 0.0f;
    const f32x4* p = (const f32x4*)(x + (size_t)row * D_FEAT);
    f32x4 a = p[lane];
    f32x4 b = p[lane + 64];
    float s = a[0]*a[0] + a[1]*a[1] + a[2]*a[2] + a[3]*a[3]
            + b[0]*b[0] + b[1]*b[1] + b[2]*b[2] + b[3]*b[3];
    #pragma unroll
    for (int m = 32; m >= 1; m >>= 1) s += __shfl_xor(s, m, 64);
    const float inv = 1.0f / fmaxf(sqrtf(s), 1e-12f);
    bf16x4 o0 = { (__bf16)(a[0]*inv), (__bf16)(a[1]*inv), (__bf16)(a[2]*inv), (__bf16)(a[3]*inv) };
    bf16x4 o1 = { (__bf16)(b[0]*inv), (__bf16)(b[1]*inv), (__bf16)(b[2]*inv), (__bf16)(b[3]*inv) };
    *(bf16x4*)(xn + (size_t)row * D_FEAT + lane * 4)       = o0;
    *(bf16x4*)(xn + (size_t)row * D_FEAT + 256 + lane * 4) = o1;
}

// ---------------- kernel 2: normalize weight rows -> bf16 -----------------
// BW-bound: 205 MB read + 102 MB write. Near HBM floor (~55-60 us).
__global__ void k_wnorm(const float* __restrict__ w, __bf16* __restrict__ wn) {
    const int row  = blockIdx.x * 4 + (threadIdx.x >> 6);   // 25000 * 4 = 100000 exact
    const int lane = threadIdx.x & 63;
    const f32x4* p = (const f32x4*)(w + (size_t)row * D_FEAT);
    f32x4 a = p[lane * 2];
    f32x4 b = p[lane * 2 + 1];
    float s = a[0]*a[0] + a[1]*a[1] + a[2]*a[2] + a[3]*a[3]
            + b[0]*b[0] + b[1]*b[1] + b[2]*b[2] + b[3]*b[3];
    #pragma unroll
    for (int m = 32; m >= 1; m >>= 1) s += __shfl_xor(s, m, 64);
    const float inv = 1.0f / fmaxf(sqrtf(s), 1e-12f);
    bf16x8 o;
    o[0] = (__bf16)(a[0]*inv); o[1] = (__bf16)(a[1]*inv);
    o[2] = (__bf16)(a[2]*inv); o[3] = (__bf16)(a[3]*inv);
    o[4] = (__bf16)(b[0]*inv); o[5] = (__bf16)(b[1]*inv);
    o[6] = (__bf16)(b[2]*inv); o[7] = (__bf16)(b[3]*inv);
    *(bf16x8*)(wn + (size_t)row * D_FEAT + lane * 8) = o;
}

// ---------------- kernel 3: bf16 GEMM 128x128, 32x32x16 MFMA --------------
// Round-2's VERIFIED sync skeleton (2 buffers, vmcnt(4), two barriers per
// k-step) unchanged. Changes vs round 2:
//  - 8x mfma_32x32x16 per k-step instead of 16x mfma_16x16x32 (same FLOPs,
//    same 8 ds_read_b128, half the MFMA instructions)
//  - staging base pointers hoisted; all per-kt addresses fold to immediates
__global__ __launch_bounds__(256, 4) void k_gemm(
        const __bf16* __restrict__ xn, const __bf16* __restrict__ wn,
        const int* __restrict__ y,
        float* __restrict__ psum, float* __restrict__ tlogit) {

    __shared__ __align__(16) __bf16 As[2][4096];   // [buf][q*128+row][8] : 16 KB
    __shared__ __align__(16) __bf16 Bs[2][4096];   // [buf][q*128+row][8] : 16 KB
    __shared__ int   ys[128];
    __shared__ float red[2][128];

    const int tid = threadIdx.x;
    // XCD-aware swizzle: 3128 = 8*391 exact, XCD x gets [x*391, (x+1)*391)
    const int wg = (blockIdx.x & 7) * (4 * NBN / 8) + (blockIdx.x >> 3);
    const int bm = wg & 3;
    const int bn = wg >> 2;

    if (tid < 128) ys[tid] = y[bm * 128 + tid];

    const int wave = tid >> 6;
    const int lane = tid & 63;
    const int wm   = wave >> 1;     // 0..1 : 64-row half
    const int wn_  = wave & 1;      // 0..1 : 64-col half
    const int l31  = lane & 31;
    const int lh   = lane >> 5;     // 0..1

    f32x16 acc[2][2];
    #pragma unroll
    for (int i = 0; i < 2; ++i)
        #pragma unroll
        for (int j = 0; j < 2; ++j)
            #pragma unroll
            for (int e = 0; e < 16; ++e) acc[i][j][e] = 0.0f;

    // hoisted staging bases: chunk c=tid -> (qc=tid>>7, rc=tid&127);
    // chunk c=tid+256 -> same row, qc+2 -> base + 16 elements.
    const __bf16* gA0 = xn + (size_t)(bm * 128 + (tid & 127)) * D_FEAT + (tid >> 7) * 8;
    int grow = bn * 128 + (tid & 127); if (grow > C_CLS - 1) grow = C_CLS - 1;
    const __bf16* gB0 = wn + (size_t)grow * D_FEAT + (tid >> 7) * 8;

    #define STAGE(s, kt_) do {                                                          \
        async_copy16(gA0 + (kt_) * 32,      &As[s][(size_t)tid * 8]);                   \
        async_copy16(gA0 + (kt_) * 32 + 16, &As[s][(size_t)(tid + 256) * 8]);           \
        async_copy16(gB0 + (kt_) * 32,      &Bs[s][(size_t)tid * 8]);                   \
        async_copy16(gB0 + (kt_) * 32 + 16, &Bs[s][(size_t)(tid + 256) * 8]);           \
    } while (0)

    STAGE(0, 0);
    STAGE(1, 1);

    #pragma unroll
    for (int kt = 0; kt < 16; ++kt) {
        const int cur = kt & 1;

        // tile kt's 4 loads done; tile kt+1's 4 stay in flight
        if (kt < 15) asm volatile("s_waitcnt vmcnt(4)" ::: "memory");
        else         asm volatile("s_waitcnt vmcnt(0)" ::: "memory");
        __builtin_amdgcn_s_barrier();

        // fragments: lane -> row = l31, k = lh*8+j within each K=16 slice.
        // LDS elem index = q*1024 + r*8, q = ks*2+lh, r = w*64 + t*32 + l31.
        bf16x8 aF[2][2], bF[2][2];
        #pragma unroll
        for (int ks = 0; ks < 2; ++ks) {
            #pragma unroll
            for (int mi = 0; mi < 2; ++mi)
                aF[ks][mi] = *(const bf16x8*)&As[cur][(ks*2 + lh) * 1024 + wm * 512 + mi * 256 + l31 * 8];
            #pragma unroll
            for (int ni = 0; ni < 2; ++ni)
                bF[ks][ni] = *(const bf16x8*)&Bs[cur][(ks*2 + lh) * 1024 + wn_ * 512 + ni * 256 + l31 * 8];
        }

        // all reads of buf[cur] retired -> safe to restage it for tile kt+2
        asm volatile("s_waitcnt lgkmcnt(0)" ::: "memory");
        __builtin_amdgcn_s_barrier();
        if (kt < 14) STAGE(cur, kt + 2);

        #pragma unroll
        for (int ks = 0; ks < 2; ++ks)
            #pragma unroll
            for (int mi = 0; mi < 2; ++mi)
                #pragma unroll
                for (int ni = 0; ni < 2; ++ni)
                    acc[mi][ni] = __builtin_amdgcn_mfma_f32_32x32x16_bf16(
                        aF[ks][mi], bF[ks][ni], acc[mi][ni], 0, 0, 0);
    }
    #undef STAGE

    // ---- epilogue: cos -> margin -> exp(logit-64) -> per-row partials ----
    // C/D layout (32x32): col = lane&31, row = (r&3) + 8*(r>>2) + 4*lh.
    #pragma unroll
    for (int mi = 0; mi < 2; ++mi) {
        float rs[16];
        #pragma unroll
        for (int r = 0; r < 16; ++r) rs[r] = 0.0f;
        #pragma unroll
        for (int ni = 0; ni < 2; ++ni) {
            const int gcol = bn * 128 + wn_ * 64 + ni * 32 + l31;
            const bool colv = (gcol < C_CLS);
            #pragma unroll
            for (int r = 0; r < 16; ++r) {
                const int lrow = wm * 64 + mi * 32 + (r & 3) + 8 * (r >> 2) + 4 * lh;
                const float cosv = acc[mi][ni][r];
                const float sinv = sqrtf(fmaxf(1.0f - cosv * cosv, 0.0f));
                const float phi  = (cosv > TH_) ? (cosv * COSM - sinv * SINM) : (cosv - MM_);
                const bool ist   = colv && (gcol == ys[lrow]);
                const float logit = 64.0f * (ist ? phi : cosv);
                if (ist) tlogit[bm * 128 + lrow] = logit;
                rs[r] += colv ? __expf(logit - 64.0f) : 0.0f;
            }
        }
        #pragma unroll
        for (int r = 0; r < 16; ++r) {
            float v = rs[r];
            v += __shfl_xor(v, 1, 64);
            v += __shfl_xor(v, 2, 64);
            v += __shfl_xor(v, 4, 64);
            v += __shfl_xor(v, 8, 64);
            v += __shfl_xor(v, 16, 64);
            if (l31 == 0)
                red[wn_][wm * 64 + mi * 32 + (r & 3) + 8 * (r >> 2) + 4 * lh] = v;
        }
    }
    __syncthreads();
    if (tid < 128) {
        const float v = red[0][tid] + red[1][tid];
        psum[(size_t)(bm * 128 + tid) * NBN + bn] = v;
    }
}

// ---------------- kernel 4: per-row reduce + loss -------------------------
__global__ void k_final(const float* __restrict__ psum, const float* __restrict__ tlogit,
                        float* __restrict__ out) {
    const int row = blockIdx.x * 4 + (threadIdx.x >> 6);   // 128 blocks x 4 rows
    const int l   = threadIdx.x & 63;
    const float* p = psum + (size_t)row * NBN;
    float s = 0.0f;
    for (int i = l; i < NBN; i += 64) s += p[i];
    #pragma unroll
    for (int m = 32; m >= 1; m >>= 1) s += __shfl_xor(s, m, 64);
    if (l == 0) {
        const float loss = logf(s) + 64.0f - tlogit[row];
        atomicAdd(out, loss * (1.0f / 512.0f));
    }
}

extern "C" void kernel_launch(void* const* d_in, const int* in_sizes, int n_in,
                              void* d_out, int out_size, void* d_ws, size_t ws_size,
                              hipStream_t stream) {
    const float* x = (const float*)d_in[0];
    const int*   y = (const int*)d_in[1];
    const float* w = (const float*)d_in[2];

    char* ws = (char*)d_ws;
    __bf16* xn     = (__bf16*)ws;                               // 524288 B
    float*  psum   = (float*)(ws + 524288);                     // 512*782*4 = 1601536 B
    float*  tlogit = (float*)(ws + 524288 + 1601536);           // 2048 B
    __bf16* wn     = (__bf16*)(ws + 524288 + 1601536 + 2048);   // 102400000 B
    float*  out    = (float*)d_out;

    hipLaunchKernelGGL(k_xnorm, dim3(512), dim3(64), 0, stream, x, xn, out);
    hipLaunchKernelGGL(k_wnorm, dim3(25000), dim3(256), 0, stream, w, wn);
    hipLaunchKernelGGL(k_gemm, dim3(4 * NBN), dim3(256), 0, stream, xn, wn, y, psum, tlogit);
    hipLaunchKernelGGL(k_final, dim3(128), dim3(256), 0, stream, psum, tlogit, out);
}

// Round 7
// 415.488 us; speedup vs baseline: 1.0570x; 1.0570x over previous
//
#include <hip/hip_runtime.h>
#include <hip/hip_bf16.h>
#include <cstdint>
#include <cstddef>

#define C_CLS   100000
#define D_FEAT  512
#define B_ROWS  512
#define NBN     782          /* ceil(100000/128) */
#define NBLK    (4 * NBN)    /* 3128 gemm blocks */

#define COSM 0.8775825618903728f
#define SINM 0.479425538604203f
#define TH_  (-0.8775825618903728f)
#define MM_  0.2397127693021015f   /* sin(0.5)*0.5 */

typedef __bf16 bf16x8 __attribute__((ext_vector_type(8)));
typedef float  f32x4  __attribute__((ext_vector_type(4)));

typedef __attribute__((address_space(3))) void lds_void;
typedef const __attribute__((address_space(1))) void g_void;

__device__ __forceinline__ void async_copy16(const void* g, void* l) {
    __builtin_amdgcn_global_load_lds((g_void*)g, (lds_void*)l, 16, 0, 0);
}

// ---------------- kernel 1: normalize ALL rows (w then x) -> bf16 ---------
// blocks 0..24999 handle w rows (4/block); blocks 25000..25127 handle x rows.
// Block 25000 additionally zeroes row_sum[512] and the ticket counter.
__global__ void k_norm(const float* __restrict__ x, const float* __restrict__ w,
                       __bf16* __restrict__ xn, __bf16* __restrict__ wn,
                       float* __restrict__ row_sum, int* __restrict__ counter) {
    const int r4   = blockIdx.x * 4 + (threadIdx.x >> 6);
    const int lane = threadIdx.x & 63;
    const float* src;
    __bf16*      dst;
    if (r4 < C_CLS) {
        src = w  + (size_t)r4 * D_FEAT;
        dst = wn + (size_t)r4 * D_FEAT;
    } else {
        src = x  + (size_t)(r4 - C_CLS) * D_FEAT;
        dst = xn + (size_t)(r4 - C_CLS) * D_FEAT;
    }
    const f32x4* p = (const f32x4*)src;
    f32x4 a = p[lane * 2];
    f32x4 b = p[lane * 2 + 1];
    float s = a[0]*a[0] + a[1]*a[1] + a[2]*a[2] + a[3]*a[3]
            + b[0]*b[0] + b[1]*b[1] + b[2]*b[2] + b[3]*b[3];
    #pragma unroll
    for (int m = 32; m >= 1; m >>= 1) s += __shfl_xor(s, m, 64);
    const float inv = 1.0f / fmaxf(sqrtf(s), 1e-12f);
    bf16x8 o;
    o[0] = (__bf16)(a[0]*inv); o[1] = (__bf16)(a[1]*inv);
    o[2] = (__bf16)(a[2]*inv); o[3] = (__bf16)(a[3]*inv);
    o[4] = (__bf16)(b[0]*inv); o[5] = (__bf16)(b[1]*inv);
    o[6] = (__bf16)(b[2]*inv); o[7] = (__bf16)(b[3]*inv);
    *(bf16x8*)(dst + lane * 8) = o;

    if (blockIdx.x == C_CLS / 4) {          // block 25000 (an x-block)
        row_sum[threadIdx.x]       = 0.0f;
        row_sum[threadIdx.x + 256] = 0.0f;
        if (threadIdx.x == 0) *counter = 0;
    }
}

// ---------------- kernel 2: bf16 MFMA GEMM + fused finalization -----------
// Round-2's measured-best inner loop (16x16x32, 2 buffers, vmcnt(4), two
// barriers per k-step) unchanged. Epilogue: per-row exp-sums atomicAdd into
// row_sum[512]; tlogit via atomicExch (coherence-point visibility); then a
// device-scope ticket -- the LAST block re-reads row_sum/tlogit with
// atomic reads (atomicAdd(p,0.0f), immune to cross-XCD L2 staleness) and
// writes the final mean loss. Eliminates the k_final dispatch.
__global__ __launch_bounds__(256, 4) void k_gemm(
        const __bf16* __restrict__ xn, const __bf16* __restrict__ wn,
        const int* __restrict__ y,
        float* __restrict__ row_sum, float* __restrict__ tlogit,
        int* __restrict__ counter, float* __restrict__ out) {

    __shared__ __align__(16) __bf16 As[2][4096];   // [buf][quad*128+row][8] : 16 KB
    __shared__ __align__(16) __bf16 Bs[2][4096];   // [buf][quad*128+row][8] : 16 KB
    __shared__ int   ys[128];
    __shared__ float red[2][128];
    __shared__ int   lastflag;
    __shared__ float pr[4];

    const int tid = threadIdx.x;
    // XCD-aware swizzle: 3128 = 8*391 exact, XCD x gets [x*391, (x+1)*391)
    const int wg = (blockIdx.x & 7) * (NBLK / 8) + (blockIdx.x >> 3);
    const int bm = wg & 3;
    const int bn = wg >> 2;

    if (tid < 128) ys[tid] = y[bm * 128 + tid];

    const int wave = tid >> 6;
    const int lane = tid & 63;
    const int wm   = wave >> 1;     // 0..1
    const int wn_  = wave & 1;      // 0..1
    const int quad = lane >> 4;     // 0..3
    const int l15  = lane & 15;

    f32x4 acc[4][4];
    #pragma unroll
    for (int i = 0; i < 4; ++i)
        #pragma unroll
        for (int j = 0; j < 4; ++j) acc[i][j] = (f32x4){0.f, 0.f, 0.f, 0.f};

    // stage tile kt_ into buffer s: A and B each 512 x 16B chunks,
    // chunk c -> quad=c>>7, row=c&127. 4 global_load_lds / thread / tile.
    #define STAGE(s, kt_) do {                                                          \
        const int k0_ = (kt_) * 32;                                                     \
        _Pragma("unroll")                                                               \
        for (int i_ = 0; i_ < 2; ++i_) {                                                \
            const int c_ = tid + i_ * 256;                                              \
            const int qc_ = c_ >> 7, rc_ = c_ & 127;                                    \
            async_copy16(xn + (size_t)(bm * 128 + rc_) * D_FEAT + k0_ + qc_ * 8,        \
                         &As[s][c_ * 8]);                                               \
        }                                                                               \
        _Pragma("unroll")                                                               \
        for (int i_ = 0; i_ < 2; ++i_) {                                                \
            const int c_ = tid + i_ * 256;                                              \
            const int qc_ = c_ >> 7, rc_ = c_ & 127;                                    \
            int grow_ = bn * 128 + rc_; if (grow_ > C_CLS - 1) grow_ = C_CLS - 1;       \
            async_copy16(wn + (size_t)grow_ * D_FEAT + k0_ + qc_ * 8,                   \
                         &Bs[s][c_ * 8]);                                               \
        }                                                                               \
    } while (0)

    STAGE(0, 0);
    STAGE(1, 1);

    #pragma unroll
    for (int kt = 0; kt < 16; ++kt) {
        const int cur = kt & 1;

        // tile kt's 4 loads done; tile kt+1's 4 stay in flight
        if (kt < 15) asm volatile("s_waitcnt vmcnt(4)" ::: "memory");
        else         asm volatile("s_waitcnt vmcnt(0)" ::: "memory");
        __builtin_amdgcn_s_barrier();

        bf16x8 af[4];
        #pragma unroll
        for (int mi = 0; mi < 4; ++mi)
            af[mi] = *(const bf16x8*)&As[cur][(quad * 128 + wm * 64 + mi * 16 + l15) * 8];
        bf16x8 bfr[4];
        #pragma unroll
        for (int ni = 0; ni < 4; ++ni)
            bfr[ni] = *(const bf16x8*)&Bs[cur][(quad * 128 + wn_ * 64 + ni * 16 + l15) * 8];

        // all reads of buf[cur] retired -> safe to restage it
        asm volatile("s_waitcnt lgkmcnt(0)" ::: "memory");
        __builtin_amdgcn_s_barrier();
        if (kt < 14) STAGE(cur, kt + 2);

        #pragma unroll
        for (int mi = 0; mi < 4; ++mi)
            #pragma unroll
            for (int ni = 0; ni < 4; ++ni)
                acc[mi][ni] = __builtin_amdgcn_mfma_f32_16x16x32_bf16(af[mi], bfr[ni], acc[mi][ni], 0, 0, 0);
    }
    #undef STAGE

    // ---- epilogue: cos -> margin -> exp(logit-64) -> per-row partials ----
    #pragma unroll
    for (int mi = 0; mi < 4; ++mi) {
        float rs[4] = {0.f, 0.f, 0.f, 0.f};
        #pragma unroll
        for (int ni = 0; ni < 4; ++ni) {
            const int gcol = bn * 128 + wn_ * 64 + ni * 16 + l15;
            const bool colv = (gcol < C_CLS);
            #pragma unroll
            for (int reg = 0; reg < 4; ++reg) {
                const int lrow = wm * 64 + mi * 16 + quad * 4 + reg;
                const float cosv = acc[mi][ni][reg];
                const float sinv = sqrtf(fmaxf(1.0f - cosv * cosv, 0.0f));
                const float phi  = (cosv > TH_) ? (cosv * COSM - sinv * SINM) : (cosv - MM_);
                const bool ist   = colv && (gcol == ys[lrow]);
                const float logit = 64.0f * (ist ? phi : cosv);
                if (ist) atomicExch(&tlogit[bm * 128 + lrow], logit);
                rs[reg] += colv ? __expf(logit - 64.0f) : 0.0f;
            }
        }
        #pragma unroll
        for (int reg = 0; reg < 4; ++reg) {
            float v = rs[reg];
            v += __shfl_xor(v, 8, 64);
            v += __shfl_xor(v, 4, 64);
            v += __shfl_xor(v, 2, 64);
            v += __shfl_xor(v, 1, 64);
            if (l15 == 0) red[wn_][wm * 64 + mi * 16 + quad * 4 + reg] = v;
        }
    }
    __syncthreads();
    if (tid < 128) {
        const float v = red[0][tid] + red[1][tid];
        atomicAdd(&row_sum[bm * 128 + tid], v);
    }

    // ---- ticket: last block finalizes the loss ---------------------------
    // __syncthreads() drains this block's atomics (vmcnt(0) before barrier);
    // all writes above are device-scope atomics -> already at the coherence
    // point when retired.
    __syncthreads();
    if (tid == 0) {
        const int t = atomicAdd(counter, 1);
        lastflag = (t == NBLK - 1) ? 1 : 0;
    }
    __syncthreads();
    if (lastflag) {
        float part = 0.0f;
        #pragma unroll
        for (int i = 0; i < 2; ++i) {
            const int row = tid + i * 256;
            const float rsv = atomicAdd(&row_sum[row], 0.0f);   // coherent read
            const float tlv = atomicAdd(&tlogit[row], 0.0f);    // coherent read
            part += logf(rsv) + 64.0f - tlv;
        }
        #pragma unroll
        for (int m = 32; m >= 1; m >>= 1) part += __shfl_xor(part, m, 64);
        if ((tid & 63) == 0) pr[tid >> 6] = part;
        __syncthreads();
        if (tid == 0)
            out[0] = (pr[0] + pr[1] + pr[2] + pr[3]) * (1.0f / 512.0f);
    }
}

extern "C" void kernel_launch(void* const* d_in, const int* in_sizes, int n_in,
                              void* d_out, int out_size, void* d_ws, size_t ws_size,
                              hipStream_t stream) {
    const float* x = (const float*)d_in[0];
    const int*   y = (const int*)d_in[1];
    const float* w = (const float*)d_in[2];

    char* ws = (char*)d_ws;
    __bf16* xn      = (__bf16*)ws;                                // 524288 B
    __bf16* wn      = (__bf16*)(ws + 524288);                     // 102400000 B
    float*  row_sum = (float*)(ws + 524288 + 102400000);          // 2048 B
    float*  tlogit  = (float*)(ws + 524288 + 102400000 + 2048);   // 2048 B
    int*    counter = (int*)(ws + 524288 + 102400000 + 4096);     // 4 B
    float*  out     = (float*)d_out;

    hipLaunchKernelGGL(k_norm, dim3((C_CLS + B_ROWS) / 4), dim3(256), 0, stream,
                       x, w, xn, wn, row_sum, counter);
    hipLaunchKernelGGL(k_gemm, dim3(NBLK), dim3(256), 0, stream,
                       xn, wn, y, row_sum, tlogit, counter, out);
}